// Round 5
// baseline (405.080 us; speedup 1.0000x reference)
//
#include <hip/hip_runtime.h>
#include <math.h>

// QuadraticAttention on MI355X — round 16: 256^2 8-wave QKV GEMM + swizzle.
// r15 post-mortem: qkvz at 51.5us is ~90% of its LDS-read roofline (12
// waves/CU x 8 ds_read_b128/K-step = 1152cy/CU-step vs 768cy MFMA; measured
// 1290). Wave-tile area sets FLOP/LDS-byte: 64x64=32 -> 128x64=43.7 FLOP/B.
// New qkvz: BM=BN=256, BK=64, 8 waves (2m x 4n), wave=128x64, 64 MFMA/wave
// per K-tile. 2x64KB LDS dbuf, depth-1 counted vmcnt(8) + raw barriers
// (r14 discipline, 2 barriers/tile). T2 swizzle: lds16B-chunk = g16 ^
// (row&7), applied on global src (linear gload_lds dst) and on ds_read
// (row&7 == l15&7 -> lane-const XOR). Epilogues in two half passes via
// 128x264 stage. Grid (4,16,3)=192 blocks, 1 blk/CU (128KB LDS).
// gemm_out (r14), attn (r15), cvt unchanged.

typedef float  f32x4  __attribute__((ext_vector_type(4)));
typedef short  bf16x8 __attribute__((ext_vector_type(8)));
typedef float  vf4    __attribute__((ext_vector_type(4)));
typedef unsigned short u16x4 __attribute__((ext_vector_type(4)));

static __device__ __forceinline__ unsigned short f2bf(float f) {
    union { float f; unsigned int i; } c; c.f = f;
    unsigned int x = c.i;
    return (unsigned short)((x + 0x7fffu + ((x >> 16) & 1u)) >> 16);
}
static __device__ __forceinline__ f32x4 shfl_xor4(f32x4 v, int m) {
    f32x4 r;
    r[0] = __shfl_xor(v[0], m); r[1] = __shfl_xor(v[1], m);
    r[2] = __shfl_xor(v[2], m); r[3] = __shfl_xor(v[3], m);
    return r;
}
static __device__ __forceinline__ f32x4 rsq4(f32x4 v) {
    f32x4 r;
#pragma unroll
    for (int i = 0; i < 4; i++) r[i] = rsqrtf(v[i] * (1.0f / 64.0f) + 1.1920929e-07f);
    return r;
}
// async 16B/lane global -> LDS
static __device__ __forceinline__ void cp16(const unsigned short* g, unsigned short* l) {
    __builtin_amdgcn_global_load_lds(
        (const __attribute__((address_space(1))) unsigned int*)g,
        (__attribute__((address_space(3))) unsigned int*)l, 16, 0, 0);
}

#define FOR_M(X)  X(0) X(1) X(2) X(3)
#define FOR_M8(X) X(0) X(1) X(2) X(3) X(4) X(5) X(6) X(7)
#define FOR_MN2(X) X(0,0) X(0,1) X(0,2) X(0,3) X(1,0) X(1,1) X(1,2) X(1,3)
#define FOR_MN84(X) X(0,0) X(0,1) X(0,2) X(0,3) X(1,0) X(1,1) X(1,2) X(1,3) \
                    X(2,0) X(2,1) X(2,2) X(2,3) X(3,0) X(3,1) X(3,2) X(3,3) \
                    X(4,0) X(4,1) X(4,2) X(4,3) X(5,0) X(5,1) X(5,2) X(5,3) \
                    X(6,0) X(6,1) X(6,2) X(6,3) X(7,0) X(7,1) X(7,2) X(7,3)

#define MF(c,a,b) c = __builtin_amdgcn_mfma_f32_16x16x32_bf16(a, b, c, 0, 0, 0);

// ---------------------------------------------------------------------------
__global__ __launch_bounds__(256) void cvt_all(
    const float* __restrict__ x,  const float* __restrict__ Wq,
    const float* __restrict__ Wk, const float* __restrict__ Wv,
    const float* __restrict__ Wo,
    unsigned short* __restrict__ xb,  unsigned short* __restrict__ Wqb,
    unsigned short* __restrict__ Wkb, unsigned short* __restrict__ Wvb,
    unsigned short* __restrict__ Wob, int nx4, int nw4)
{
    int i = blockIdx.x * 256 + threadIdx.x;
    const float* s; unsigned short* d; int li;
    if (i < nx4) { s = x; d = xb; li = i; }
    else {
        int idx = i - nx4;
        int r = idx / nw4; li = idx - r * nw4;
        if (r >= 4) return;
        s = (r == 0) ? Wq : (r == 1) ? Wk : (r == 2) ? Wv : Wo;
        d = (r == 0) ? Wqb : (r == 1) ? Wkb : (r == 2) ? Wvb : Wob;
    }
    vf4 v = *(const vf4*)(s + (size_t)li * 4);
    u16x4 o;
#pragma unroll
    for (int j = 0; j < 4; j++) o[j] = f2bf(v[j]);
    *(u16x4*)(d + (size_t)li * 4) = o;
}

// ---------------------------------------------------------------------------
#define SS2 264   // epilogue stage row stride (elems), 128 x 264 = 33792 ush

// ---------------------------------------------------------------------------
// Per-matrix GEMM (z = 0:q 1:k 2:v). 512 threads / 8 waves (wy 0..1 m,
// wx 0..3 n), 256x256 tile, wave owns 128x64. BK=64. 2x64KB dbuf, counted
// vmcnt(8), XOR-swizzled LDS. Epilogue: q/k bias+rmsnorm+rope (2 row-half
// passes); v bias + transposed per-head store (2 col-half passes).
// ---------------------------------------------------------------------------
__global__ __launch_bounds__(512, 2) void gemm_qkvz(
    const unsigned short* __restrict__ xb,
    const unsigned short* __restrict__ Wqb,
    const unsigned short* __restrict__ Wkb,
    const unsigned short* __restrict__ Wvb,
    const float* __restrict__ bqf, const float* __restrict__ bkf, const float* __restrict__ bvf,
    const float* __restrict__ nwp,
    unsigned short* __restrict__ qb, unsigned short* __restrict__ kb,
    unsigned short* __restrict__ vT)
{
    const int K = 1024;
    __shared__ unsigned short smem[65536];   // 128KB: 2 x (A[256][64] + B[256][64])
    const int z = blockIdx.z;
    const unsigned short* Wb = (z == 0) ? Wqb : (z == 1) ? Wkb : Wvb;
    const float* bias = (z == 0) ? bqf : (z == 1) ? bkf : bvf;
    const int tid = threadIdx.x;
    const int n0 = blockIdx.x * 256;
    const int m0 = blockIdx.y * 256;
    const int lane = tid & 63, wid = tid >> 6;   // 8 waves
    const int wy = wid >> 2, wx = wid & 3;       // wave = 128m x 64n
    const int l15 = lane & 15, quad = lane >> 4;
    const int sw = (l15 & 7) << 4;               // read-side swizzle (bytes)
    // staging coords: round j covers rows j*64 + (tid>>3), 16B-chunk tid&7
    const int srow = tid >> 3;                   // 0..63
    const int sc16 = tid & 7;

#define Z_DECL_ACC(mi,ni) f32x4 c##mi##ni = {0.f, 0.f, 0.f, 0.f};
    FOR_MN84(Z_DECL_ACC)

// stage one K-tile (A[256][64] + B[256][64]) into buffer BUF with
// inverse-swizzled global source (linear LDS dest). 8 cp16 / thread.
#define ZSTAGE(BUF, KT) { \
        unsigned short* dstb = smem + (BUF) * 32768; \
        _Pragma("unroll") \
        for (int j = 0; j < 4; j++) { \
            const int row = j * 64 + srow; \
            const int gc = sc16 ^ (row & 7); \
            cp16(xb + (size_t)(m0 + row) * K + (KT) + gc * 8, \
                 dstb + row * 64 + sc16 * 8); \
            cp16(Wb + (size_t)(n0 + row) * K + (KT) + gc * 8, \
                 dstb + 16384 + row * 64 + sc16 * 8); \
        } }

#define ZA_DECL(mi) const bf16x8 a##mi = *(const bf16x8*)&As_[(wy * 128 + (mi) * 16 + l15) * 64 + offk];
#define ZB_DECL(ni) const bf16x8 b##ni = *(const bf16x8*)&Bs_[(wx * 64 + (ni) * 16 + l15) * 64 + offk];
#define ZMF_ROW(mi) MF(c##mi##0, a##mi, b0) MF(c##mi##1, a##mi, b1) \
                    MF(c##mi##2, a##mi, b2) MF(c##mi##3, a##mi, b3)

#define ZCOMPUTE(BUF) { \
        const unsigned short* As_ = smem + (BUF) * 32768; \
        const unsigned short* Bs_ = As_ + 16384; \
        _Pragma("unroll") \
        for (int ks = 0; ks < 2; ks++) { \
            const int offk = ((ks * 64 + quad * 16) ^ sw) >> 1; \
            FOR_M8(ZA_DECL) \
            ZB_DECL(0) ZB_DECL(1) ZB_DECL(2) ZB_DECL(3) \
            FOR_M8(ZMF_ROW) \
        } }

#define VM8 asm volatile("s_waitcnt vmcnt(8)" ::: "memory");
#define VM0 asm volatile("s_waitcnt vmcnt(0)" ::: "memory");
#define LG0 asm volatile("s_waitcnt lgkmcnt(0)" ::: "memory");
#define BAR __builtin_amdgcn_s_barrier();

    // ---- K loop: 16 tiles of BK=64, depth-1 counted-vmcnt pipeline ----
    ZSTAGE(0, 0)
    for (int p = 0; p < 7; ++p) {
        ZSTAGE(1, (2 * p + 1) * 64)
        VM8 BAR
        ZCOMPUTE(0)
        LG0 BAR
        ZSTAGE(0, (2 * p + 2) * 64)
        VM8 BAR
        ZCOMPUTE(1)
        LG0 BAR
    }
    ZSTAGE(1, 15 * 64)
    VM8 BAR
    ZCOMPUTE(0)
    LG0 BAR
    VM0 BAR
    ZCOMPUTE(1)
    __syncthreads();   // all reads done; smem reused as epilogue stage

    // ---- bias (all paths) ----
    const float bs0 = bias[n0 + wx * 64 + l15];
    const float bs1 = bias[n0 + wx * 64 + 16 + l15];
    const float bs2 = bias[n0 + wx * 64 + 32 + l15];
    const float bs3 = bias[n0 + wx * 64 + 48 + l15];
#define Z_BIAS(mi) c##mi##0 += bs0; c##mi##1 += bs1; c##mi##2 += bs2; c##mi##3 += bs3;
    FOR_M8(Z_BIAS)

    if (z < 2) {
        // ---- q/k: rmsnorm (per 64-dim head row) + rope; two row-half passes ----
        const float nww0 = nwp[l15],      nww1 = nwp[16 + l15];
        const float nww2 = nwp[32 + l15], nww3 = nwp[48 + l15];
        const float lf0 = expf(-(float)l15 * 0.28782313662425572f);      // ln(1e4)/32
        const float lf1 = expf(-(float)(l15 + 16) * 0.28782313662425572f);

#define Z_S2(mi) f32x4 s2_##mi = c##mi##0*c##mi##0 + c##mi##1*c##mi##1 + \
                                 c##mi##2*c##mi##2 + c##mi##3*c##mi##3; \
        s2_##mi = s2_##mi + shfl_xor4(s2_##mi, 1); \
        s2_##mi = s2_##mi + shfl_xor4(s2_##mi, 2); \
        s2_##mi = s2_##mi + shfl_xor4(s2_##mi, 4); \
        s2_##mi = s2_##mi + shfl_xor4(s2_##mi, 8); \
        s2_##mi = rsq4(s2_##mi);
        FOR_M8(Z_S2)

        unsigned short* dst = z ? kb : qb;

#define Z_ROPE_ONE(mi,ni,NW,CS,SN) { \
            float vn = c##mi##ni[r] * s2v[r] * NW; \
            float pt = __shfl_xor(vn, 1); \
            float rot = (lane & 1) ? pt : -pt; \
            smem[sr * SS2 + wx * 64 + (ni) * 16 + l15] = f2bf((vn * (CS) + rot * (SN)) * 0.125f); }
#define Z_ROPE_MI(mi) { f32x4 s2v = s2_##mi; \
            _Pragma("unroll") \
            for (int r = 0; r < 4; r++) { \
                const int sr = (mi) * 16 + quad * 4 + r; \
                const float t = (float)((m0 + wy * 128 + sr) & 2047); \
                const float a0 = t * lf0, a1 = t * lf1; \
                const float cs0 = cosf(a0), sn0 = sinf(a0); \
                const float cs1 = cosf(a1), sn1 = sinf(a1); \
                Z_ROPE_ONE(mi,0,nww0,cs0,sn0) Z_ROPE_ONE(mi,1,nww1,cs1,sn1) \
                Z_ROPE_ONE(mi,2,nww2,cs0,sn0) Z_ROPE_ONE(mi,3,nww3,cs1,sn1) } }

#pragma unroll
        for (int h2 = 0; h2 < 2; h2++) {
            if (wy == h2) { FOR_M8(Z_ROPE_MI) }
            __syncthreads();
#pragma unroll
            for (int it = 0; it < 8; it++) {
                const int linear = tid + it * 512;
                const int row = linear >> 5, cb = linear & 31;
                *(bf16x8*)(dst + (size_t)(m0 + h2 * 128 + row) * 1024 + n0 + cb * 8) =
                    *(const bf16x8*)&smem[row * SS2 + cb * 8];
            }
            __syncthreads();
        }
    } else {
        // ---- v: transposed per-head store; two col-half passes ----
        const int b = m0 >> 11, tok0 = m0 & 2047;
#define Z_VST(mi,ni) { _Pragma("unroll") \
            for (int r = 0; r < 4; r++) { \
                const int mrow = wy * 128 + (mi) * 16 + quad * 4 + r; \
                smem[((wx & 1) * 64 + (ni) * 16 + l15) * SS2 + mrow] = f2bf(c##mi##ni[r]); } }
#pragma unroll
        for (int c2 = 0; c2 < 2; c2++) {
            if ((wx >> 1) == c2) { FOR_MN84(Z_VST) }
            __syncthreads();
#pragma unroll
            for (int it = 0; it < 8; it++) {
                const int linear = tid + it * 512;
                const int rowd = linear >> 5, cb = linear & 31;
                const int ncol = c2 * 128 + rowd;
                const int head_g = (n0 >> 6) + (ncol >> 6);
                const int d = ncol & 63;
                *(bf16x8*)(vT + (((size_t)b * 16 + head_g) * 64 + d) * 2048 + tok0 + cb * 8) =
                    *(const bf16x8*)&smem[rowd * SS2 + cb * 8];
            }
            __syncthreads();
        }
    }
}

// ---------------------------------------------------------------------------
// Output GEMM + residual. 512 threads / 8 waves, wave = 32m x 64n, 3-buffer
// depth-2 counted-vmcnt pipeline (3 x 16KB). (r14, unchanged)
// ---------------------------------------------------------------------------
__global__ __launch_bounds__(512) void gemm_out(
    const unsigned short* __restrict__ zb,
    const unsigned short* __restrict__ Wob,
    const float* __restrict__ x, float* __restrict__ out, int M)
{
    const int K = 1024;
    __shared__ unsigned short smem[24576];
    const int tid = threadIdx.x;
    const int n0 = blockIdx.x * 128;
    const int m0 = blockIdx.y * 128;
    const int lane = tid & 63, wid = tid >> 6;
    const int wy = wid >> 1, wx = wid & 1;
    const int l15 = lane & 15, quad = lane >> 4;
    const int r16 = lane >> 2;
    const int c8  = (lane & 3) * 8;

#define G_DECL_ACC(mi,ni) f32x4 c##mi##ni = {0.f, 0.f, 0.f, 0.f};
    FOR_MN2(G_DECL_ACC)

#define O_STAGE(BUF, KT) { \
        unsigned short* dstb = smem + (BUF) * 8192; \
        _Pragma("unroll") \
        for (int j = 0; j < 2; j++) { \
            const int ch = wid * 2 + j; \
            const int mat = ch >> 3; \
            const int row = (ch & 7) * 16 + r16; \
            const unsigned short* g = (mat == 0) \
                ? zb  + (size_t)(m0 + row) * K + (KT) + c8 \
                : Wob + (size_t)(n0 + row) * K + (KT) + c8; \
            cp16(g, &dstb[ch * 512]); \
        } }

#define O_COMPUTE(BUF) { \
        const unsigned short* As_ = smem + (BUF) * 8192; \
        const unsigned short* Ws_ = As_ + 4096; \
        const bf16x8 a0 = *(const bf16x8*)&As_[(wy * 32 +  0 + l15) * 32 + quad * 8]; \
        const bf16x8 a1 = *(const bf16x8*)&As_[(wy * 32 + 16 + l15) * 32 + quad * 8]; \
        const bf16x8 b0 = *(const bf16x8*)&Ws_[(wx * 64 +  0 + l15) * 32 + quad * 8]; \
        const bf16x8 b1 = *(const bf16x8*)&Ws_[(wx * 64 + 16 + l15) * 32 + quad * 8]; \
        const bf16x8 b2 = *(const bf16x8*)&Ws_[(wx * 64 + 32 + l15) * 32 + quad * 8]; \
        const bf16x8 b3 = *(const bf16x8*)&Ws_[(wx * 64 + 48 + l15) * 32 + quad * 8]; \
        MF(c00,a0,b0) MF(c01,a0,b1) MF(c02,a0,b2) MF(c03,a0,b3) \
        MF(c10,a1,b0) MF(c11,a1,b1) MF(c12,a1,b2) MF(c13,a1,b3) }

    O_STAGE(0, 0)
    O_STAGE(1, 32)
    {
        int cbuf = 0, sbuf = 2;
        for (int it = 0; it < 31; ++it) {
            asm volatile("s_waitcnt vmcnt(2)" ::: "memory");
            __builtin_amdgcn_s_barrier();
            if (it < 30) { O_STAGE(sbuf, (it + 2) * 32) }
            O_COMPUTE(cbuf)
            asm volatile("s_waitcnt lgkmcnt(0)" ::: "memory");
            cbuf = (cbuf == 2) ? 0 : cbuf + 1;
            sbuf = (sbuf == 2) ? 0 : sbuf + 1;
        }
        asm volatile("s_waitcnt vmcnt(0)" ::: "memory");
        __builtin_amdgcn_s_barrier();
        O_COMPUTE(cbuf)
    }

#define G_OUTST(mi,ni) { _Pragma("unroll") \
        for (int r = 0; r < 4; r++) { \
            const int m = m0 + wy * 32 + (mi) * 16 + quad * 4 + r; \
            const int n = n0 + wx * 64 + (ni) * 16 + l15; \
            out[(size_t)m * 1024 + n] = c##mi##ni[r] + x[(size_t)m * 1024 + n]; } }
    FOR_MN2(G_OUTST)
}

// ---------------------------------------------------------------------------
// Causal quadratic attention (r15: balanced 1D grid). Unchanged.
// ---------------------------------------------------------------------------
__global__ __launch_bounds__(256) void attn_mfma(
    const unsigned short* __restrict__ qb, const unsigned short* __restrict__ kb,
    const unsigned short* __restrict__ vT, unsigned short* __restrict__ zb)
{
    __shared__ unsigned short Qs[128 * 72];
    __shared__ unsigned short Ks[64 * 72];
    __shared__ unsigned short Vs[64 * 72];
    __shared__ unsigned short Pm[128 * 72];
    const int tid = threadIdx.x;

    const int bid = blockIdx.x;
    const int halfsz = gridDim.x >> 1;
    const int half = (bid >= halfsz) ? 1 : 0;
    const int r = bid - half * halfsz;
    const int qt = half ? (r & 7) : 15 - (r & 7);
    const int bh = r >> 3;

    const int b = bh >> 4, h = bh & 15;
    const int lane = tid & 63, wq = tid >> 6;
    const int l15 = lane & 15, quad = lane >> 4;
    const size_t tokbase = (size_t)b * 2048;
    const int q0 = qt * 128;

#pragma unroll
    for (int j = 0; j < 4; j++) {
        const int u = tid + j * 256;
        const int row = u >> 3, seg = (u & 7) * 8;
        bf16x8 v = *(const bf16x8*)(qb + (tokbase + q0 + row) * 1024 + h * 64 + seg);
        *(bf16x8*)&Qs[row * 72 + seg] = v;
    }
    __syncthreads();
    const bf16x8 aq00 = *(const bf16x8*)&Qs[(wq * 32 + l15) * 72 + quad * 8];
    const bf16x8 aq01 = *(const bf16x8*)&Qs[(wq * 32 + l15) * 72 + 32 + quad * 8];
    const bf16x8 aq10 = *(const bf16x8*)&Qs[(wq * 32 + 16 + l15) * 72 + quad * 8];
    const bf16x8 aq11 = *(const bf16x8*)&Qs[(wq * 32 + 16 + l15) * 72 + 32 + quad * 8];

    const int kr = tid >> 3;
    const int sg = (tid & 7) * 8;

    bf16x8 pk0, pk1, pv0, pv1;
#define A_GLB(KT) { \
        pk0 = *(const bf16x8*)(kb + (tokbase + (KT) * 64 + kr) * 1024 + h * 64 + sg); \
        pk1 = *(const bf16x8*)(kb + (tokbase + (KT) * 64 + kr + 32) * 1024 + h * 64 + sg); \
        pv0 = *(const bf16x8*)(vT + ((size_t)bh * 64 + kr) * 2048 + (KT) * 64 + sg); \
        pv1 = *(const bf16x8*)(vT + ((size_t)bh * 64 + kr + 32) * 2048 + (KT) * 64 + sg); }

#define A_DECL_Z(mi,n) f32x4 z_##mi##n = {0.f, 0.f, 0.f, 0.f};
    FOR_MN2(A_DECL_Z)

    const int nkt = 2 * qt + 2;
    A_GLB(0)
    for (int kt = 0; kt < nkt; kt++) {
        __syncthreads();
        *(bf16x8*)&Ks[kr * 72 + sg] = pk0;
        *(bf16x8*)&Ks[(kr + 32) * 72 + sg] = pk1;
        *(bf16x8*)&Vs[kr * 72 + sg] = pv0;
        *(bf16x8*)&Vs[(kr + 32) * 72 + sg] = pv1;
        __syncthreads();
        if (kt + 1 < nkt) A_GLB(kt + 1)

#define A_DECL_S(mi,n) f32x4 s_##mi##n = {0.f, 0.f, 0.f, 0.f};
        FOR_MN2(A_DECL_S)
#define A_QKH(KS, AQ0, AQ1) { \
        bf16x8 b0 = *(const bf16x8*)&Ks[(l15) * 72 + (KS) * 32 + quad * 8]; \
        bf16x8 b1 = *(const bf16x8*)&Ks[(16 + l15) * 72 + (KS) * 32 + quad * 8]; \
        bf16x8 b2 = *(const bf16x8*)&Ks[(32 + l15) * 72 + (KS) * 32 + quad * 8]; \
        bf16x8 b3 = *(const bf16x8*)&Ks[(48 + l15) * 72 + (KS) * 32 + quad * 8]; \
        s_00 = __builtin_amdgcn_mfma_f32_16x16x32_bf16(AQ0, b0, s_00, 0, 0, 0); \
        s_01 = __builtin_amdgcn_mfma_f32_16x16x32_bf16(AQ0, b1, s_01, 0, 0, 0); \
        s_02 = __builtin_amdgcn_mfma_f32_16x16x32_bf16(AQ0, b2, s_02, 0, 0, 0); \
        s_03 = __builtin_amdgcn_mfma_f32_16x16x32_bf16(AQ0, b3, s_03, 0, 0, 0); \
        s_10 = __builtin_amdgcn_mfma_f32_16x16x32_bf16(AQ1, b0, s_10, 0, 0, 0); \
        s_11 = __builtin_amdgcn_mfma_f32_16x16x32_bf16(AQ1, b1, s_11, 0, 0, 0); \
        s_12 = __builtin_amdgcn_mfma_f32_16x16x32_bf16(AQ1, b2, s_12, 0, 0, 0); \
        s_13 = __builtin_amdgcn_mfma_f32_16x16x32_bf16(AQ1, b3, s_13, 0, 0, 0); }
        A_QKH(0, aq00, aq10)
        A_QKH(1, aq01, aq11)

        const bool needmask = (kt >= 2 * qt);
#define A_PSTORE(mi,n) { \
        f32x4 p4 = s_##mi##n * s_##mi##n; \
        if (needmask) { _Pragma("unroll") \
            for (int r2 = 0; r2 < 4; r2++) \
                if (kt * 64 + (n) * 16 + l15 > q0 + wq * 32 + (mi) * 16 + quad * 4 + r2) p4[r2] = 0.f; } \
        _Pragma("unroll") \
        for (int r2 = 0; r2 < 4; r2++) \
            Pm[(wq * 32 + (mi) * 16 + quad * 4 + r2) * 72 + (n) * 16 + l15] = f2bf(p4[r2]); }
        FOR_MN2(A_PSTORE)

#define A_PVH(KS) { \
        bf16x8 ap0 = *(const bf16x8*)&Pm[(wq * 32 + l15) * 72 + (KS) * 32 + quad * 8]; \
        bf16x8 ap1 = *(const bf16x8*)&Pm[(wq * 32 + 16 + l15) * 72 + (KS) * 32 + quad * 8]; \
        bf16x8 u0 = *(const bf16x8*)&Vs[(l15) * 72 + (KS) * 32 + quad * 8]; \
        bf16x8 u1 = *(const bf16x8*)&Vs[(16 + l15) * 72 + (KS) * 32 + quad * 8]; \
        bf16x8 u2 = *(const bf16x8*)&Vs[(32 + l15) * 72 + (KS) * 32 + quad * 8]; \
        bf16x8 u3 = *(const bf16x8*)&Vs[(48 + l15) * 72 + (KS) * 32 + quad * 8]; \
        z_00 = __builtin_amdgcn_mfma_f32_16x16x32_bf16(ap0, u0, z_00, 0, 0, 0); \
        z_01 = __builtin_amdgcn_mfma_f32_16x16x32_bf16(ap0, u1, z_01, 0, 0, 0); \
        z_02 = __builtin_amdgcn_mfma_f32_16x16x32_bf16(ap0, u2, z_02, 0, 0, 0); \
        z_03 = __builtin_amdgcn_mfma_f32_16x16x32_bf16(ap0, u3, z_03, 0, 0, 0); \
        z_10 = __builtin_amdgcn_mfma_f32_16x16x32_bf16(ap1, u0, z_10, 0, 0, 0); \
        z_11 = __builtin_amdgcn_mfma_f32_16x16x32_bf16(ap1, u1, z_11, 0, 0, 0); \
        z_12 = __builtin_amdgcn_mfma_f32_16x16x32_bf16(ap1, u2, z_12, 0, 0, 0); \
        z_13 = __builtin_amdgcn_mfma_f32_16x16x32_bf16(ap1, u3, z_13, 0, 0, 0); }
        A_PVH(0)
        A_PVH(1)
    }

#define A_ZST(mi,n) { _Pragma("unroll") \
        for (int r2 = 0; r2 < 4; r2++) \
            Pm[(wq * 32 + (mi) * 16 + quad * 4 + r2) * 72 + (n) * 16 + l15] = f2bf(z_##mi##n[r2]); }
    FOR_MN2(A_ZST)
#pragma unroll
    for (int it = 0; it < 4; it++) {
        const int linear = it * 64 + lane;
        const int row = linear >> 3, cb = linear & 7;
        *(bf16x8*)(zb + (tokbase + q0 + wq * 32 + row) * 1024 + h * 64 + cb * 8) =
            *(const bf16x8*)&Pm[(wq * 32 + row) * 72 + cb * 8];
    }
}

// ---------------------------------------------------------------------------
extern "C" void kernel_launch(void* const* d_in, const int* in_sizes, int n_in,
                              void* d_out, int out_size, void* d_ws, size_t ws_size,
                              hipStream_t stream)
{
    const float* x  = (const float*)d_in[0];
    const float* Wq = (const float*)d_in[1];
    const float* bq = (const float*)d_in[2];
    const float* Wk = (const float*)d_in[3];
    const float* bk = (const float*)d_in[4];
    const float* Wv = (const float*)d_in[5];
    const float* bv = (const float*)d_in[6];
    const float* Wo = (const float*)d_in[7];
    const float* nw = (const float*)d_in[8];
    float* out = (float*)d_out;

    const int D = 1024;
    const int M = in_sizes[0] / D;   // B*S = 4096

    unsigned short* xbb = (unsigned short*)d_ws;         // M*D
    unsigned short* Wqb = xbb + (size_t)M * D;           // D*D
    unsigned short* Wkb = Wqb + (size_t)D * D;
    unsigned short* Wvb = Wkb + (size_t)D * D;
    unsigned short* Wob = Wvb + (size_t)D * D;
    unsigned short* qbw = Wob + (size_t)D * D;           // M*D
    unsigned short* kbw = qbw + (size_t)M * D;
    unsigned short* vTw = kbw + (size_t)M * D;
    unsigned short* zbw = vTw + (size_t)M * D;

    const int nx4 = M * D / 4, nw4 = D * D / 4;
    const int ncvt = nx4 + 4 * nw4;
    cvt_all<<<(ncvt + 255) / 256, 256, 0, stream>>>(
        x, Wq, Wk, Wv, Wo, xbb, Wqb, Wkb, Wvb, Wob, nx4, nw4);

    gemm_qkvz<<<dim3(D / 256, M / 256, 3), 512, 0, stream>>>(
        xbb, Wqb, Wkb, Wvb, bq, bk, bv, nw, qbw, kbw, vTw);

    attn_mfma<<<dim3((M / 2048) * 16 * 16), 256, 0, stream>>>(qbw, kbw, vTw, zbw);

    gemm_out<<<dim3(D / 128, M / 128), 512, 0, stream>>>(zbw, Wob, x, out, M);
}

// Round 6
// 196.891 us; speedup vs baseline: 2.0574x; 2.0574x over previous
//
#include <hip/hip_runtime.h>
#include <math.h>

// QuadraticAttention on MI355X — round 17: revert r16, upgrade gemm_out+attn.
// r16 post-mortem: 256^2 8-wave qkvz SPILLED (WRITE 88MB vs 24.5 expected =
// ~63MB scratch in K-loop; MfmaUtil 4%, 5x slower). 32 f32x4 accs + frags +
// epilogue liveness > 2-wave/SIMD budget. Also r15 was NOT LDS-bound
// (ds_read_b128 ~4cy at 256B/clk, not 12): its limiter is VALU+stall mix.
// r17: (1) gemm_qkvz = exact r15 code (proven 51.5us, 3 blk/CU, 72 VGPR);
// (2) gemm_out rebuilt as r15-style: 256thr/4 waves/wave 64x64 (ratio 2.0
// vs old 1.33), 3-buf 48KB depth-2 vmcnt(4); (3) attn + s_setprio(1) around
// MFMA clusters (T5, proven +4-7% on phase-diverse attn, m191).

typedef float  f32x4  __attribute__((ext_vector_type(4)));
typedef short  bf16x8 __attribute__((ext_vector_type(8)));
typedef float  vf4    __attribute__((ext_vector_type(4)));
typedef unsigned short u16x4 __attribute__((ext_vector_type(4)));

static __device__ __forceinline__ unsigned short f2bf(float f) {
    union { float f; unsigned int i; } c; c.f = f;
    unsigned int x = c.i;
    return (unsigned short)((x + 0x7fffu + ((x >> 16) & 1u)) >> 16);
}
static __device__ __forceinline__ f32x4 shfl_xor4(f32x4 v, int m) {
    f32x4 r;
    r[0] = __shfl_xor(v[0], m); r[1] = __shfl_xor(v[1], m);
    r[2] = __shfl_xor(v[2], m); r[3] = __shfl_xor(v[3], m);
    return r;
}
static __device__ __forceinline__ f32x4 rsq4(f32x4 v) {
    f32x4 r;
#pragma unroll
    for (int i = 0; i < 4; i++) r[i] = rsqrtf(v[i] * (1.0f / 64.0f) + 1.1920929e-07f);
    return r;
}
// async 16B/lane global -> LDS
static __device__ __forceinline__ void cp16(const unsigned short* g, unsigned short* l) {
    __builtin_amdgcn_global_load_lds(
        (const __attribute__((address_space(1))) unsigned int*)g,
        (__attribute__((address_space(3))) unsigned int*)l, 16, 0, 0);
}

#define FOR_M(X)  X(0) X(1) X(2) X(3)
#define FOR_MN(X) X(0,0) X(0,1) X(0,2) X(0,3) X(1,0) X(1,1) X(1,2) X(1,3) \
                  X(2,0) X(2,1) X(2,2) X(2,3) X(3,0) X(3,1) X(3,2) X(3,3)
#define FOR_MN2(X) X(0,0) X(0,1) X(0,2) X(0,3) X(1,0) X(1,1) X(1,2) X(1,3)

#define MF(c,a,b) c = __builtin_amdgcn_mfma_f32_16x16x32_bf16(a, b, c, 0, 0, 0);

// ---------------------------------------------------------------------------
__global__ __launch_bounds__(256) void cvt_all(
    const float* __restrict__ x,  const float* __restrict__ Wq,
    const float* __restrict__ Wk, const float* __restrict__ Wv,
    const float* __restrict__ Wo,
    unsigned short* __restrict__ xb,  unsigned short* __restrict__ Wqb,
    unsigned short* __restrict__ Wkb, unsigned short* __restrict__ Wvb,
    unsigned short* __restrict__ Wob, int nx4, int nw4)
{
    int i = blockIdx.x * 256 + threadIdx.x;
    const float* s; unsigned short* d; int li;
    if (i < nx4) { s = x; d = xb; li = i; }
    else {
        int idx = i - nx4;
        int r = idx / nw4; li = idx - r * nw4;
        if (r >= 4) return;
        s = (r == 0) ? Wq : (r == 1) ? Wk : (r == 2) ? Wv : Wo;
        d = (r == 0) ? Wqb : (r == 1) ? Wkb : (r == 2) ? Wvb : Wob;
    }
    vf4 v = *(const vf4*)(s + (size_t)li * 4);
    u16x4 o;
#pragma unroll
    for (int j = 0; j < 4; j++) o[j] = f2bf(v[j]);
    *(u16x4*)(d + (size_t)li * 4) = o;
}

// ---------------------------------------------------------------------------
#define SS 136   // epilogue stage row stride (elems)

// ---------------------------------------------------------------------------
// Per-matrix GEMM (z = 0:q 1:k 2:v). 256 threads / 4 waves, 128x128 tile,
// wave (wy,wx) owns 64m x 64n. BK=32, 3-buffer depth-2 counted-vmcnt
// pipeline. 768 blocks = 3 blocks/CU (48KB LDS each).  [r15, proven]
// ---------------------------------------------------------------------------
__global__ __launch_bounds__(256, 3) void gemm_qkvz(
    const unsigned short* __restrict__ xb,
    const unsigned short* __restrict__ Wqb,
    const unsigned short* __restrict__ Wkb,
    const unsigned short* __restrict__ Wvb,
    const float* __restrict__ bqf, const float* __restrict__ bkf, const float* __restrict__ bvf,
    const float* __restrict__ nwp,
    unsigned short* __restrict__ qb, unsigned short* __restrict__ kb,
    unsigned short* __restrict__ vT)
{
    const int K = 1024;
    __shared__ unsigned short smem[24576];   // 48KB: 3 staging bufs (16KB); epi stage aliases
    const int z = blockIdx.z;
    const unsigned short* Wb = (z == 0) ? Wqb : (z == 1) ? Wkb : Wvb;
    const float* bias = (z == 0) ? bqf : (z == 1) ? bkf : bvf;
    const int tid = threadIdx.x;
    const int n0 = blockIdx.x * 128;
    const int m0 = blockIdx.y * 128;
    const int lane = tid & 63, wid = tid >> 6;   // 4 waves
    const int wy = wid >> 1, wx = wid & 1;       // wave = 64m x 64n
    const int l15 = lane & 15, quad = lane >> 4;
    const int r16 = lane >> 2;
    const int c8  = (lane & 3) * 8;

#define Z_DECL_ACC(mi,ni) f32x4 c##mi##ni = {0.f, 0.f, 0.f, 0.f};
    FOR_MN(Z_DECL_ACC)

#define Z_STAGE(BUF, KT) { \
        unsigned short* dstb = smem + (BUF) * 8192; \
        _Pragma("unroll") \
        for (int j = 0; j < 4; j++) { \
            const int ch = wid * 4 + j;          /* 0..15, 16 rows each */ \
            const int mat = ch >> 3;             /* 0:A(x) 1:W */ \
            const int row = (ch & 7) * 16 + r16; \
            const unsigned short* g = mat \
                ? Wb + (size_t)(n0 + row) * K + (KT) + c8 \
                : xb + (size_t)(m0 + row) * K + (KT) + c8; \
            cp16(g, &dstb[ch * 512]); \
        } }

#define Z_COMPUTE(BUF) { \
        const unsigned short* As_ = smem + (BUF) * 8192; \
        const unsigned short* Bs_ = As_ + 4096; \
        const bf16x8 a0 = *(const bf16x8*)&As_[(wy * 64 +  0 + l15) * 32 + quad * 8]; \
        const bf16x8 a1 = *(const bf16x8*)&As_[(wy * 64 + 16 + l15) * 32 + quad * 8]; \
        const bf16x8 a2 = *(const bf16x8*)&As_[(wy * 64 + 32 + l15) * 32 + quad * 8]; \
        const bf16x8 a3 = *(const bf16x8*)&As_[(wy * 64 + 48 + l15) * 32 + quad * 8]; \
        const bf16x8 b0 = *(const bf16x8*)&Bs_[(wx * 64 +  0 + l15) * 32 + quad * 8]; \
        const bf16x8 b1 = *(const bf16x8*)&Bs_[(wx * 64 + 16 + l15) * 32 + quad * 8]; \
        const bf16x8 b2 = *(const bf16x8*)&Bs_[(wx * 64 + 32 + l15) * 32 + quad * 8]; \
        const bf16x8 b3 = *(const bf16x8*)&Bs_[(wx * 64 + 48 + l15) * 32 + quad * 8]; \
        MF(c00,a0,b0) MF(c01,a0,b1) MF(c02,a0,b2) MF(c03,a0,b3) \
        MF(c10,a1,b0) MF(c11,a1,b1) MF(c12,a1,b2) MF(c13,a1,b3) \
        MF(c20,a2,b0) MF(c21,a2,b1) MF(c22,a2,b2) MF(c23,a2,b3) \
        MF(c30,a3,b0) MF(c31,a3,b1) MF(c32,a3,b2) MF(c33,a3,b3) }

    // ---- pipelined K-loop: 32 tiles, depth-2 prefetch, counted vmcnt ----
    Z_STAGE(0, 0)
    Z_STAGE(1, 32)
    {
        int cbuf = 0, sbuf = 2;
        for (int it = 0; it < 31; ++it) {
            asm volatile("s_waitcnt vmcnt(4)" ::: "memory");  // tile `it` resident
            __builtin_amdgcn_s_barrier();                     // no drain; fences prev reads
            if (it < 30) { Z_STAGE(sbuf, (it + 2) * 32) }     // into buffer freed at it-1
            Z_COMPUTE(cbuf)
            asm volatile("s_waitcnt lgkmcnt(0)" ::: "memory"); // pin my LDS reads pre-barrier
            cbuf = (cbuf == 2) ? 0 : cbuf + 1;
            sbuf = (sbuf == 2) ? 0 : sbuf + 1;
        }
        asm volatile("s_waitcnt vmcnt(0)" ::: "memory");
        __builtin_amdgcn_s_barrier();
        Z_COMPUTE(cbuf)                                        // tile 31
    }
    __syncthreads();   // full drain once; smem reused as epilogue stage

    // bias (all paths)
    const float bs0 = bias[n0 + wx * 64 + l15];
    const float bs1 = bias[n0 + wx * 64 + 16 + l15];
    const float bs2 = bias[n0 + wx * 64 + 32 + l15];
    const float bs3 = bias[n0 + wx * 64 + 48 + l15];
#define Z_BIAS(mi) c##mi##0 += bs0; c##mi##1 += bs1; c##mi##2 += bs2; c##mi##3 += bs3;
    FOR_M(Z_BIAS)

    if (z < 2) {
        // ---- q/k: rmsnorm (per 64-dim head row) + rope + store ----
        const float nww0 = nwp[l15],      nww1 = nwp[16 + l15];
        const float nww2 = nwp[32 + l15], nww3 = nwp[48 + l15];
        const float lf0 = expf(-(float)l15 * 0.28782313662425572f);      // ln(1e4)/32
        const float lf1 = expf(-(float)(l15 + 16) * 0.28782313662425572f);

#define Z_S2(mi) f32x4 s2_##mi = c##mi##0*c##mi##0 + c##mi##1*c##mi##1 + \
                                 c##mi##2*c##mi##2 + c##mi##3*c##mi##3; \
        s2_##mi = s2_##mi + shfl_xor4(s2_##mi, 1); \
        s2_##mi = s2_##mi + shfl_xor4(s2_##mi, 2); \
        s2_##mi = s2_##mi + shfl_xor4(s2_##mi, 4); \
        s2_##mi = s2_##mi + shfl_xor4(s2_##mi, 8); \
        s2_##mi = rsq4(s2_##mi);
        FOR_M(Z_S2)

#define Z_ROPE_ONE(mi,ni,NW,CS,SN) { \
            float vn = c##mi##ni[r] * s2v[r] * NW; \
            float pt = __shfl_xor(vn, 1); \
            float rot = (lane & 1) ? pt : -pt; \
            smem[mrow * SS + wx * 64 + (ni) * 16 + l15] = f2bf((vn * (CS) + rot * (SN)) * 0.125f); }
#define Z_ROPE_MI(mi) { f32x4 s2v = s2_##mi; \
            _Pragma("unroll") \
            for (int r = 0; r < 4; r++) { \
                const int mrow = wy * 64 + (mi) * 16 + quad * 4 + r; \
                const float t = (float)((m0 + mrow) & 2047); \
                const float a0 = t * lf0, a1 = t * lf1; \
                const float cs0 = cosf(a0), sn0 = sinf(a0); \
                const float cs1 = cosf(a1), sn1 = sinf(a1); \
                Z_ROPE_ONE(mi,0,nww0,cs0,sn0) Z_ROPE_ONE(mi,1,nww1,cs1,sn1) \
                Z_ROPE_ONE(mi,2,nww2,cs0,sn0) Z_ROPE_ONE(mi,3,nww3,cs1,sn1) } }
        FOR_M(Z_ROPE_MI)

        __syncthreads();
        unsigned short* dst = z ? kb : qb;
#pragma unroll
        for (int it = 0; it < 8; it++) {
            const int linear = tid + it * 256;
            const int row = linear >> 4, cb = linear & 15;
            *(bf16x8*)(dst + (size_t)(m0 + row) * 1024 + n0 + cb * 8) =
                *(const bf16x8*)&smem[row * SS + cb * 8];
        }
    } else {
        // ---- v: transposed per-head store ----
#define Z_VST(mi,ni) { _Pragma("unroll") \
            for (int r = 0; r < 4; r++) { \
                const int mrow = wy * 64 + (mi) * 16 + quad * 4 + r; \
                smem[(wx * 64 + (ni) * 16 + l15) * SS + mrow] = f2bf(c##mi##ni[r]); } }
        FOR_MN(Z_VST)
        __syncthreads();
        const int b = m0 >> 11, tok0 = m0 & 2047;
#pragma unroll
        for (int it = 0; it < 8; it++) {
            const int linear = tid + it * 256;
            const int rowd = linear >> 4, cb = linear & 15;
            const int head_g = (n0 >> 6) + (rowd >> 6);
            const int d = rowd & 63;
            *(bf16x8*)(vT + (((size_t)b * 16 + head_g) * 64 + d) * 2048 + tok0 + cb * 8) =
                *(const bf16x8*)&smem[rowd * SS + cb * 8];
        }
    }
}

// ---------------------------------------------------------------------------
// Output GEMM + residual. r17: r15-style structure — 256 threads / 4 waves,
// 128x128 tile, wave 64x64 (16 accs, MFMA:read = 2.0 vs old 1.33), 3-buf
// 48KB depth-2 vmcnt(4) pipeline. Epilogue: f32 residual add.
// ---------------------------------------------------------------------------
__global__ __launch_bounds__(256, 3) void gemm_out(
    const unsigned short* __restrict__ zb,
    const unsigned short* __restrict__ Wob,
    const float* __restrict__ x, float* __restrict__ out, int M)
{
    const int K = 1024;
    __shared__ unsigned short smem[24576];   // 3 bufs x (A[128][32] + W[128][32])
    const int tid = threadIdx.x;
    const int n0 = blockIdx.x * 128;
    const int m0 = blockIdx.y * 128;
    const int lane = tid & 63, wid = tid >> 6;
    const int wy = wid >> 1, wx = wid & 1;       // wave = 64m x 64n
    const int l15 = lane & 15, quad = lane >> 4;
    const int r16 = lane >> 2;
    const int c8  = (lane & 3) * 8;

#define G_DECL_ACC(mi,ni) f32x4 c##mi##ni = {0.f, 0.f, 0.f, 0.f};
    FOR_MN(G_DECL_ACC)

#define O_STAGE(BUF, KT) { \
        unsigned short* dstb = smem + (BUF) * 8192; \
        _Pragma("unroll") \
        for (int j = 0; j < 4; j++) { \
            const int ch = wid * 4 + j;          /* 0..15, 16 rows each */ \
            const int mat = ch >> 3;             /* 0:A(z) 1:W */ \
            const int row = (ch & 7) * 16 + r16; \
            const unsigned short* g = mat \
                ? Wob + (size_t)(n0 + row) * K + (KT) + c8 \
                : zb  + (size_t)(m0 + row) * K + (KT) + c8; \
            cp16(g, &dstb[ch * 512]); \
        } }

#define O_COMPUTE(BUF) { \
        const unsigned short* As_ = smem + (BUF) * 8192; \
        const unsigned short* Bs_ = As_ + 4096; \
        const bf16x8 a0 = *(const bf16x8*)&As_[(wy * 64 +  0 + l15) * 32 + quad * 8]; \
        const bf16x8 a1 = *(const bf16x8*)&As_[(wy * 64 + 16 + l15) * 32 + quad * 8]; \
        const bf16x8 a2 = *(const bf16x8*)&As_[(wy * 64 + 32 + l15) * 32 + quad * 8]; \
        const bf16x8 a3 = *(const bf16x8*)&As_[(wy * 64 + 48 + l15) * 32 + quad * 8]; \
        const bf16x8 b0 = *(const bf16x8*)&Bs_[(wx * 64 +  0 + l15) * 32 + quad * 8]; \
        const bf16x8 b1 = *(const bf16x8*)&Bs_[(wx * 64 + 16 + l15) * 32 + quad * 8]; \
        const bf16x8 b2 = *(const bf16x8*)&Bs_[(wx * 64 + 32 + l15) * 32 + quad * 8]; \
        const bf16x8 b3 = *(const bf16x8*)&Bs_[(wx * 64 + 48 + l15) * 32 + quad * 8]; \
        MF(c00,a0,b0) MF(c01,a0,b1) MF(c02,a0,b2) MF(c03,a0,b3) \
        MF(c10,a1,b0) MF(c11,a1,b1) MF(c12,a1,b2) MF(c13,a1,b3) \
        MF(c20,a2,b0) MF(c21,a2,b1) MF(c22,a2,b2) MF(c23,a2,b3) \
        MF(c30,a3,b0) MF(c31,a3,b1) MF(c32,a3,b2) MF(c33,a3,b3) }

    O_STAGE(0, 0)
    O_STAGE(1, 32)
    {
        int cbuf = 0, sbuf = 2;
        for (int it = 0; it < 31; ++it) {
            asm volatile("s_waitcnt vmcnt(4)" ::: "memory");
            __builtin_amdgcn_s_barrier();
            if (it < 30) { O_STAGE(sbuf, (it + 2) * 32) }
            O_COMPUTE(cbuf)
            asm volatile("s_waitcnt lgkmcnt(0)" ::: "memory");
            cbuf = (cbuf == 2) ? 0 : cbuf + 1;
            sbuf = (sbuf == 2) ? 0 : sbuf + 1;
        }
        asm volatile("s_waitcnt vmcnt(0)" ::: "memory");
        __builtin_amdgcn_s_barrier();
        O_COMPUTE(cbuf)
    }

#define G_OUTST(mi,ni) { _Pragma("unroll") \
        for (int r = 0; r < 4; r++) { \
            const int m = m0 + wy * 64 + (mi) * 16 + quad * 4 + r; \
            const int n = n0 + wx * 64 + (ni) * 16 + l15; \
            out[(size_t)m * 1024 + n] = c##mi##ni[r] + x[(size_t)m * 1024 + n]; } }
    FOR_MN(G_OUTST)
}

// ---------------------------------------------------------------------------
// Causal quadratic attention (r15 balanced grid) + T5 setprio around MFMA.
// ---------------------------------------------------------------------------
__global__ __launch_bounds__(256) void attn_mfma(
    const unsigned short* __restrict__ qb, const unsigned short* __restrict__ kb,
    const unsigned short* __restrict__ vT, unsigned short* __restrict__ zb)
{
    __shared__ unsigned short Qs[128 * 72];
    __shared__ unsigned short Ks[64 * 72];
    __shared__ unsigned short Vs[64 * 72];
    __shared__ unsigned short Pm[128 * 72];
    const int tid = threadIdx.x;

    const int bid = blockIdx.x;
    const int halfsz = gridDim.x >> 1;
    const int half = (bid >= halfsz) ? 1 : 0;
    const int r = bid - half * halfsz;
    const int qt = half ? (r & 7) : 15 - (r & 7);
    const int bh = r >> 3;

    const int b = bh >> 4, h = bh & 15;
    const int lane = tid & 63, wq = tid >> 6;
    const int l15 = lane & 15, quad = lane >> 4;
    const size_t tokbase = (size_t)b * 2048;
    const int q0 = qt * 128;

#pragma unroll
    for (int j = 0; j < 4; j++) {
        const int u = tid + j * 256;
        const int row = u >> 3, seg = (u & 7) * 8;
        bf16x8 v = *(const bf16x8*)(qb + (tokbase + q0 + row) * 1024 + h * 64 + seg);
        *(bf16x8*)&Qs[row * 72 + seg] = v;
    }
    __syncthreads();
    const bf16x8 aq00 = *(const bf16x8*)&Qs[(wq * 32 + l15) * 72 + quad * 8];
    const bf16x8 aq01 = *(const bf16x8*)&Qs[(wq * 32 + l15) * 72 + 32 + quad * 8];
    const bf16x8 aq10 = *(const bf16x8*)&Qs[(wq * 32 + 16 + l15) * 72 + quad * 8];
    const bf16x8 aq11 = *(const bf16x8*)&Qs[(wq * 32 + 16 + l15) * 72 + 32 + quad * 8];

    const int kr = tid >> 3;
    const int sg = (tid & 7) * 8;

    bf16x8 pk0, pk1, pv0, pv1;
#define A_GLB(KT) { \
        pk0 = *(const bf16x8*)(kb + (tokbase + (KT) * 64 + kr) * 1024 + h * 64 + sg); \
        pk1 = *(const bf16x8*)(kb + (tokbase + (KT) * 64 + kr + 32) * 1024 + h * 64 + sg); \
        pv0 = *(const bf16x8*)(vT + ((size_t)bh * 64 + kr) * 2048 + (KT) * 64 + sg); \
        pv1 = *(const bf16x8*)(vT + ((size_t)bh * 64 + kr + 32) * 2048 + (KT) * 64 + sg); }

#define A_DECL_Z(mi,n) f32x4 z_##mi##n = {0.f, 0.f, 0.f, 0.f};
    FOR_MN2(A_DECL_Z)

    const int nkt = 2 * qt + 2;
    A_GLB(0)
    for (int kt = 0; kt < nkt; kt++) {
        __syncthreads();
        *(bf16x8*)&Ks[kr * 72 + sg] = pk0;
        *(bf16x8*)&Ks[(kr + 32) * 72 + sg] = pk1;
        *(bf16x8*)&Vs[kr * 72 + sg] = pv0;
        *(bf16x8*)&Vs[(kr + 32) * 72 + sg] = pv1;
        __syncthreads();
        if (kt + 1 < nkt) A_GLB(kt + 1)

#define A_DECL_S(mi,n) f32x4 s_##mi##n = {0.f, 0.f, 0.f, 0.f};
        FOR_MN2(A_DECL_S)
#define A_QKH(KS, AQ0, AQ1) { \
        bf16x8 b0 = *(const bf16x8*)&Ks[(l15) * 72 + (KS) * 32 + quad * 8]; \
        bf16x8 b1 = *(const bf16x8*)&Ks[(16 + l15) * 72 + (KS) * 32 + quad * 8]; \
        bf16x8 b2 = *(const bf16x8*)&Ks[(32 + l15) * 72 + (KS) * 32 + quad * 8]; \
        bf16x8 b3 = *(const bf16x8*)&Ks[(48 + l15) * 72 + (KS) * 32 + quad * 8]; \
        s_00 = __builtin_amdgcn_mfma_f32_16x16x32_bf16(AQ0, b0, s_00, 0, 0, 0); \
        s_01 = __builtin_amdgcn_mfma_f32_16x16x32_bf16(AQ0, b1, s_01, 0, 0, 0); \
        s_02 = __builtin_amdgcn_mfma_f32_16x16x32_bf16(AQ0, b2, s_02, 0, 0, 0); \
        s_03 = __builtin_amdgcn_mfma_f32_16x16x32_bf16(AQ0, b3, s_03, 0, 0, 0); \
        s_10 = __builtin_amdgcn_mfma_f32_16x16x32_bf16(AQ1, b0, s_10, 0, 0, 0); \
        s_11 = __builtin_amdgcn_mfma_f32_16x16x32_bf16(AQ1, b1, s_11, 0, 0, 0); \
        s_12 = __builtin_amdgcn_mfma_f32_16x16x32_bf16(AQ1, b2, s_12, 0, 0, 0); \
        s_13 = __builtin_amdgcn_mfma_f32_16x16x32_bf16(AQ1, b3, s_13, 0, 0, 0); }
        __builtin_amdgcn_s_setprio(1);
        A_QKH(0, aq00, aq10)
        A_QKH(1, aq01, aq11)
        __builtin_amdgcn_s_setprio(0);

        const bool needmask = (kt >= 2 * qt);
#define A_PSTORE(mi,n) { \
        f32x4 p4 = s_##mi##n * s_##mi##n; \
        if (needmask) { _Pragma("unroll") \
            for (int r2 = 0; r2 < 4; r2++) \
                if (kt * 64 + (n) * 16 + l15 > q0 + wq * 32 + (mi) * 16 + quad * 4 + r2) p4[r2] = 0.f; } \
        _Pragma("unroll") \
        for (int r2 = 0; r2 < 4; r2++) \
            Pm[(wq * 32 + (mi) * 16 + quad * 4 + r2) * 72 + (n) * 16 + l15] = f2bf(p4[r2]); }
        FOR_MN2(A_PSTORE)

#define A_PVH(KS) { \
        bf16x8 ap0 = *(const bf16x8*)&Pm[(wq * 32 + l15) * 72 + (KS) * 32 + quad * 8]; \
        bf16x8 ap1 = *(const bf16x8*)&Pm[(wq * 32 + 16 + l15) * 72 + (KS) * 32 + quad * 8]; \
        bf16x8 u0 = *(const bf16x8*)&Vs[(l15) * 72 + (KS) * 32 + quad * 8]; \
        bf16x8 u1 = *(const bf16x8*)&Vs[(16 + l15) * 72 + (KS) * 32 + quad * 8]; \
        bf16x8 u2 = *(const bf16x8*)&Vs[(32 + l15) * 72 + (KS) * 32 + quad * 8]; \
        bf16x8 u3 = *(const bf16x8*)&Vs[(48 + l15) * 72 + (KS) * 32 + quad * 8]; \
        z_00 = __builtin_amdgcn_mfma_f32_16x16x32_bf16(ap0, u0, z_00, 0, 0, 0); \
        z_01 = __builtin_amdgcn_mfma_f32_16x16x32_bf16(ap0, u1, z_01, 0, 0, 0); \
        z_02 = __builtin_amdgcn_mfma_f32_16x16x32_bf16(ap0, u2, z_02, 0, 0, 0); \
        z_03 = __builtin_amdgcn_mfma_f32_16x16x32_bf16(ap0, u3, z_03, 0, 0, 0); \
        z_10 = __builtin_amdgcn_mfma_f32_16x16x32_bf16(ap1, u0, z_10, 0, 0, 0); \
        z_11 = __builtin_amdgcn_mfma_f32_16x16x32_bf16(ap1, u1, z_11, 0, 0, 0); \
        z_12 = __builtin_amdgcn_mfma_f32_16x16x32_bf16(ap1, u2, z_12, 0, 0, 0); \
        z_13 = __builtin_amdgcn_mfma_f32_16x16x32_bf16(ap1, u3, z_13, 0, 0, 0); }
        __builtin_amdgcn_s_setprio(1);
        A_PVH(0)
        A_PVH(1)
        __builtin_amdgcn_s_setprio(0);
    }

#define A_ZST(mi,n) { _Pragma("unroll") \
        for (int r2 = 0; r2 < 4; r2++) \
            Pm[(wq * 32 + (mi) * 16 + quad * 4 + r2) * 72 + (n) * 16 + l15] = f2bf(z_##mi##n[r2]); }
    FOR_MN2(A_ZST)
#pragma unroll
    for (int it = 0; it < 4; it++) {
        const int linear = it * 64 + lane;
        const int row = linear >> 3, cb = linear & 7;
        *(bf16x8*)(zb + (tokbase + q0 + wq * 32 + row) * 1024 + h * 64 + cb * 8) =
            *(const bf16x8*)&Pm[(wq * 32 + row) * 72 + cb * 8];
    }
}

// ---------------------------------------------------------------------------
extern "C" void kernel_launch(void* const* d_in, const int* in_sizes, int n_in,
                              void* d_out, int out_size, void* d_ws, size_t ws_size,
                              hipStream_t stream)
{
    const float* x  = (const float*)d_in[0];
    const float* Wq = (const float*)d_in[1];
    const float* bq = (const float*)d_in[2];
    const float* Wk = (const float*)d_in[3];
    const float* bk = (const float*)d_in[4];
    const float* Wv = (const float*)d_in[5];
    const float* bv = (const float*)d_in[6];
    const float* Wo = (const float*)d_in[7];
    const float* nw = (const float*)d_in[8];
    float* out = (float*)d_out;

    const int D = 1024;
    const int M = in_sizes[0] / D;   // B*S = 4096

    unsigned short* xbb = (unsigned short*)d_ws;         // M*D
    unsigned short* Wqb = xbb + (size_t)M * D;           // D*D
    unsigned short* Wkb = Wqb + (size_t)D * D;
    unsigned short* Wvb = Wkb + (size_t)D * D;
    unsigned short* Wob = Wvb + (size_t)D * D;
    unsigned short* qbw = Wob + (size_t)D * D;           // M*D
    unsigned short* kbw = qbw + (size_t)M * D;
    unsigned short* vTw = kbw + (size_t)M * D;
    unsigned short* zbw = vTw + (size_t)M * D;

    const int nx4 = M * D / 4, nw4 = D * D / 4;
    const int ncvt = nx4 + 4 * nw4;
    cvt_all<<<(ncvt + 255) / 256, 256, 0, stream>>>(
        x, Wq, Wk, Wv, Wo, xbb, Wqb, Wkb, Wvb, Wob, nx4, nw4);

    gemm_qkvz<<<dim3(D / 128, M / 128, 3), 256, 0, stream>>>(
        xbb, Wqb, Wkb, Wvb, bq, bk, bv, nw, qbw, kbw, vTw);

    attn_mfma<<<dim3((M / 2048) * 16 * 16), 256, 0, stream>>>(qbw, kbw, vTw, zbw);

    gemm_out<<<dim3(D / 128, M / 128), 256, 0, stream>>>(zbw, Wob, x, out, M);
}

// Round 7
// 185.898 us; speedup vs baseline: 2.1790x; 1.0591x over previous
//
#include <hip/hip_runtime.h>
#include <math.h>

// QuadraticAttention on MI355X — round 18: attn QBLK 128->64 for occupancy.
// r17 post-mortem: attn top at 49.8us, Occ 12.9% = the short block of each
// CU pair finishes early -> CU runs ONE 4-wave block most of the time. LDS
// floor for attn is ~9-13us; gap is concurrency. Now: QBLK=64 (4 waves x 16
// q-rows), grid 32qt x 32bh = 1024 blocks = 4 blk/CU (36.9KB LDS, lb(256,4)),
// half-remap pairs (31-x, x) -> per-CU 66 iters uniform, tail runs 2 blocks.
// Same math; mask only at kt==qt. K/V re-reads double but L2/L3-absorbed.
// gemm_qkvz (r15), gemm_out (r17), cvt unchanged.

typedef float  f32x4  __attribute__((ext_vector_type(4)));
typedef short  bf16x8 __attribute__((ext_vector_type(8)));
typedef float  vf4    __attribute__((ext_vector_type(4)));
typedef unsigned short u16x4 __attribute__((ext_vector_type(4)));

static __device__ __forceinline__ unsigned short f2bf(float f) {
    union { float f; unsigned int i; } c; c.f = f;
    unsigned int x = c.i;
    return (unsigned short)((x + 0x7fffu + ((x >> 16) & 1u)) >> 16);
}
static __device__ __forceinline__ f32x4 shfl_xor4(f32x4 v, int m) {
    f32x4 r;
    r[0] = __shfl_xor(v[0], m); r[1] = __shfl_xor(v[1], m);
    r[2] = __shfl_xor(v[2], m); r[3] = __shfl_xor(v[3], m);
    return r;
}
static __device__ __forceinline__ f32x4 rsq4(f32x4 v) {
    f32x4 r;
#pragma unroll
    for (int i = 0; i < 4; i++) r[i] = rsqrtf(v[i] * (1.0f / 64.0f) + 1.1920929e-07f);
    return r;
}
// async 16B/lane global -> LDS
static __device__ __forceinline__ void cp16(const unsigned short* g, unsigned short* l) {
    __builtin_amdgcn_global_load_lds(
        (const __attribute__((address_space(1))) unsigned int*)g,
        (__attribute__((address_space(3))) unsigned int*)l, 16, 0, 0);
}

#define FOR_M(X)  X(0) X(1) X(2) X(3)
#define FOR_MN(X) X(0,0) X(0,1) X(0,2) X(0,3) X(1,0) X(1,1) X(1,2) X(1,3) \
                  X(2,0) X(2,1) X(2,2) X(2,3) X(3,0) X(3,1) X(3,2) X(3,3)

#define MF(c,a,b) c = __builtin_amdgcn_mfma_f32_16x16x32_bf16(a, b, c, 0, 0, 0);

// ---------------------------------------------------------------------------
__global__ __launch_bounds__(256) void cvt_all(
    const float* __restrict__ x,  const float* __restrict__ Wq,
    const float* __restrict__ Wk, const float* __restrict__ Wv,
    const float* __restrict__ Wo,
    unsigned short* __restrict__ xb,  unsigned short* __restrict__ Wqb,
    unsigned short* __restrict__ Wkb, unsigned short* __restrict__ Wvb,
    unsigned short* __restrict__ Wob, int nx4, int nw4)
{
    int i = blockIdx.x * 256 + threadIdx.x;
    const float* s; unsigned short* d; int li;
    if (i < nx4) { s = x; d = xb; li = i; }
    else {
        int idx = i - nx4;
        int r = idx / nw4; li = idx - r * nw4;
        if (r >= 4) return;
        s = (r == 0) ? Wq : (r == 1) ? Wk : (r == 2) ? Wv : Wo;
        d = (r == 0) ? Wqb : (r == 1) ? Wkb : (r == 2) ? Wvb : Wob;
    }
    vf4 v = *(const vf4*)(s + (size_t)li * 4);
    u16x4 o;
#pragma unroll
    for (int j = 0; j < 4; j++) o[j] = f2bf(v[j]);
    *(u16x4*)(d + (size_t)li * 4) = o;
}

// ---------------------------------------------------------------------------
#define SS 136   // epilogue stage row stride (elems)

// ---------------------------------------------------------------------------
// Per-matrix GEMM (z = 0:q 1:k 2:v). 256 threads / 4 waves, 128x128 tile,
// wave (wy,wx) owns 64m x 64n. BK=32, 3-buffer depth-2 counted-vmcnt
// pipeline. 768 blocks = 3 blocks/CU (48KB LDS each).  [r15, proven]
// ---------------------------------------------------------------------------
__global__ __launch_bounds__(256, 3) void gemm_qkvz(
    const unsigned short* __restrict__ xb,
    const unsigned short* __restrict__ Wqb,
    const unsigned short* __restrict__ Wkb,
    const unsigned short* __restrict__ Wvb,
    const float* __restrict__ bqf, const float* __restrict__ bkf, const float* __restrict__ bvf,
    const float* __restrict__ nwp,
    unsigned short* __restrict__ qb, unsigned short* __restrict__ kb,
    unsigned short* __restrict__ vT)
{
    const int K = 1024;
    __shared__ unsigned short smem[24576];   // 48KB: 3 staging bufs (16KB); epi stage aliases
    const int z = blockIdx.z;
    const unsigned short* Wb = (z == 0) ? Wqb : (z == 1) ? Wkb : Wvb;
    const float* bias = (z == 0) ? bqf : (z == 1) ? bkf : bvf;
    const int tid = threadIdx.x;
    const int n0 = blockIdx.x * 128;
    const int m0 = blockIdx.y * 128;
    const int lane = tid & 63, wid = tid >> 6;   // 4 waves
    const int wy = wid >> 1, wx = wid & 1;       // wave = 64m x 64n
    const int l15 = lane & 15, quad = lane >> 4;
    const int r16 = lane >> 2;
    const int c8  = (lane & 3) * 8;

#define Z_DECL_ACC(mi,ni) f32x4 c##mi##ni = {0.f, 0.f, 0.f, 0.f};
    FOR_MN(Z_DECL_ACC)

#define Z_STAGE(BUF, KT) { \
        unsigned short* dstb = smem + (BUF) * 8192; \
        _Pragma("unroll") \
        for (int j = 0; j < 4; j++) { \
            const int ch = wid * 4 + j;          /* 0..15, 16 rows each */ \
            const int mat = ch >> 3;             /* 0:A(x) 1:W */ \
            const int row = (ch & 7) * 16 + r16; \
            const unsigned short* g = mat \
                ? Wb + (size_t)(n0 + row) * K + (KT) + c8 \
                : xb + (size_t)(m0 + row) * K + (KT) + c8; \
            cp16(g, &dstb[ch * 512]); \
        } }

#define Z_COMPUTE(BUF) { \
        const unsigned short* As_ = smem + (BUF) * 8192; \
        const unsigned short* Bs_ = As_ + 4096; \
        const bf16x8 a0 = *(const bf16x8*)&As_[(wy * 64 +  0 + l15) * 32 + quad * 8]; \
        const bf16x8 a1 = *(const bf16x8*)&As_[(wy * 64 + 16 + l15) * 32 + quad * 8]; \
        const bf16x8 a2 = *(const bf16x8*)&As_[(wy * 64 + 32 + l15) * 32 + quad * 8]; \
        const bf16x8 a3 = *(const bf16x8*)&As_[(wy * 64 + 48 + l15) * 32 + quad * 8]; \
        const bf16x8 b0 = *(const bf16x8*)&Bs_[(wx * 64 +  0 + l15) * 32 + quad * 8]; \
        const bf16x8 b1 = *(const bf16x8*)&Bs_[(wx * 64 + 16 + l15) * 32 + quad * 8]; \
        const bf16x8 b2 = *(const bf16x8*)&Bs_[(wx * 64 + 32 + l15) * 32 + quad * 8]; \
        const bf16x8 b3 = *(const bf16x8*)&Bs_[(wx * 64 + 48 + l15) * 32 + quad * 8]; \
        MF(c00,a0,b0) MF(c01,a0,b1) MF(c02,a0,b2) MF(c03,a0,b3) \
        MF(c10,a1,b0) MF(c11,a1,b1) MF(c12,a1,b2) MF(c13,a1,b3) \
        MF(c20,a2,b0) MF(c21,a2,b1) MF(c22,a2,b2) MF(c23,a2,b3) \
        MF(c30,a3,b0) MF(c31,a3,b1) MF(c32,a3,b2) MF(c33,a3,b3) }

    // ---- pipelined K-loop: 32 tiles, depth-2 prefetch, counted vmcnt ----
    Z_STAGE(0, 0)
    Z_STAGE(1, 32)
    {
        int cbuf = 0, sbuf = 2;
        for (int it = 0; it < 31; ++it) {
            asm volatile("s_waitcnt vmcnt(4)" ::: "memory");  // tile `it` resident
            __builtin_amdgcn_s_barrier();                     // no drain; fences prev reads
            if (it < 30) { Z_STAGE(sbuf, (it + 2) * 32) }     // into buffer freed at it-1
            Z_COMPUTE(cbuf)
            asm volatile("s_waitcnt lgkmcnt(0)" ::: "memory"); // pin my LDS reads pre-barrier
            cbuf = (cbuf == 2) ? 0 : cbuf + 1;
            sbuf = (sbuf == 2) ? 0 : sbuf + 1;
        }
        asm volatile("s_waitcnt vmcnt(0)" ::: "memory");
        __builtin_amdgcn_s_barrier();
        Z_COMPUTE(cbuf)                                        // tile 31
    }
    __syncthreads();   // full drain once; smem reused as epilogue stage

    // bias (all paths)
    const float bs0 = bias[n0 + wx * 64 + l15];
    const float bs1 = bias[n0 + wx * 64 + 16 + l15];
    const float bs2 = bias[n0 + wx * 64 + 32 + l15];
    const float bs3 = bias[n0 + wx * 64 + 48 + l15];
#define Z_BIAS(mi) c##mi##0 += bs0; c##mi##1 += bs1; c##mi##2 += bs2; c##mi##3 += bs3;
    FOR_M(Z_BIAS)

    if (z < 2) {
        // ---- q/k: rmsnorm (per 64-dim head row) + rope + store ----
        const float nww0 = nwp[l15],      nww1 = nwp[16 + l15];
        const float nww2 = nwp[32 + l15], nww3 = nwp[48 + l15];
        const float lf0 = expf(-(float)l15 * 0.28782313662425572f);      // ln(1e4)/32
        const float lf1 = expf(-(float)(l15 + 16) * 0.28782313662425572f);

#define Z_S2(mi) f32x4 s2_##mi = c##mi##0*c##mi##0 + c##mi##1*c##mi##1 + \
                                 c##mi##2*c##mi##2 + c##mi##3*c##mi##3; \
        s2_##mi = s2_##mi + shfl_xor4(s2_##mi, 1); \
        s2_##mi = s2_##mi + shfl_xor4(s2_##mi, 2); \
        s2_##mi = s2_##mi + shfl_xor4(s2_##mi, 4); \
        s2_##mi = s2_##mi + shfl_xor4(s2_##mi, 8); \
        s2_##mi = rsq4(s2_##mi);
        FOR_M(Z_S2)

#define Z_ROPE_ONE(mi,ni,NW,CS,SN) { \
            float vn = c##mi##ni[r] * s2v[r] * NW; \
            float pt = __shfl_xor(vn, 1); \
            float rot = (lane & 1) ? pt : -pt; \
            smem[mrow * SS + wx * 64 + (ni) * 16 + l15] = f2bf((vn * (CS) + rot * (SN)) * 0.125f); }
#define Z_ROPE_MI(mi) { f32x4 s2v = s2_##mi; \
            _Pragma("unroll") \
            for (int r = 0; r < 4; r++) { \
                const int mrow = wy * 64 + (mi) * 16 + quad * 4 + r; \
                const float t = (float)((m0 + mrow) & 2047); \
                const float a0 = t * lf0, a1 = t * lf1; \
                const float cs0 = cosf(a0), sn0 = sinf(a0); \
                const float cs1 = cosf(a1), sn1 = sinf(a1); \
                Z_ROPE_ONE(mi,0,nww0,cs0,sn0) Z_ROPE_ONE(mi,1,nww1,cs1,sn1) \
                Z_ROPE_ONE(mi,2,nww2,cs0,sn0) Z_ROPE_ONE(mi,3,nww3,cs1,sn1) } }
        FOR_M(Z_ROPE_MI)

        __syncthreads();
        unsigned short* dst = z ? kb : qb;
#pragma unroll
        for (int it = 0; it < 8; it++) {
            const int linear = tid + it * 256;
            const int row = linear >> 4, cb = linear & 15;
            *(bf16x8*)(dst + (size_t)(m0 + row) * 1024 + n0 + cb * 8) =
                *(const bf16x8*)&smem[row * SS + cb * 8];
        }
    } else {
        // ---- v: transposed per-head store ----
#define Z_VST(mi,ni) { _Pragma("unroll") \
            for (int r = 0; r < 4; r++) { \
                const int mrow = wy * 64 + (mi) * 16 + quad * 4 + r; \
                smem[(wx * 64 + (ni) * 16 + l15) * SS + mrow] = f2bf(c##mi##ni[r]); } }
        FOR_MN(Z_VST)
        __syncthreads();
        const int b = m0 >> 11, tok0 = m0 & 2047;
#pragma unroll
        for (int it = 0; it < 8; it++) {
            const int linear = tid + it * 256;
            const int rowd = linear >> 4, cb = linear & 15;
            const int head_g = (n0 >> 6) + (rowd >> 6);
            const int d = rowd & 63;
            *(bf16x8*)(vT + (((size_t)b * 16 + head_g) * 64 + d) * 2048 + tok0 + cb * 8) =
                *(const bf16x8*)&smem[rowd * SS + cb * 8];
        }
    }
}

// ---------------------------------------------------------------------------
// Output GEMM + residual. r17 structure: 256 threads / 4 waves, 128x128
// tile, wave 64x64, 3-buf 48KB depth-2 vmcnt(4) pipeline. (unchanged)
// ---------------------------------------------------------------------------
__global__ __launch_bounds__(256, 3) void gemm_out(
    const unsigned short* __restrict__ zb,
    const unsigned short* __restrict__ Wob,
    const float* __restrict__ x, float* __restrict__ out, int M)
{
    const int K = 1024;
    __shared__ unsigned short smem[24576];
    const int tid = threadIdx.x;
    const int n0 = blockIdx.x * 128;
    const int m0 = blockIdx.y * 128;
    const int lane = tid & 63, wid = tid >> 6;
    const int wy = wid >> 1, wx = wid & 1;       // wave = 64m x 64n
    const int l15 = lane & 15, quad = lane >> 4;
    const int r16 = lane >> 2;
    const int c8  = (lane & 3) * 8;

#define G_DECL_ACC(mi,ni) f32x4 c##mi##ni = {0.f, 0.f, 0.f, 0.f};
    FOR_MN(G_DECL_ACC)

#define O_STAGE(BUF, KT) { \
        unsigned short* dstb = smem + (BUF) * 8192; \
        _Pragma("unroll") \
        for (int j = 0; j < 4; j++) { \
            const int ch = wid * 4 + j; \
            const int mat = ch >> 3; \
            const int row = (ch & 7) * 16 + r16; \
            const unsigned short* g = mat \
                ? Wob + (size_t)(n0 + row) * K + (KT) + c8 \
                : zb  + (size_t)(m0 + row) * K + (KT) + c8; \
            cp16(g, &dstb[ch * 512]); \
        } }

#define O_COMPUTE(BUF) { \
        const unsigned short* As_ = smem + (BUF) * 8192; \
        const unsigned short* Bs_ = As_ + 4096; \
        const bf16x8 a0 = *(const bf16x8*)&As_[(wy * 64 +  0 + l15) * 32 + quad * 8]; \
        const bf16x8 a1 = *(const bf16x8*)&As_[(wy * 64 + 16 + l15) * 32 + quad * 8]; \
        const bf16x8 a2 = *(const bf16x8*)&As_[(wy * 64 + 32 + l15) * 32 + quad * 8]; \
        const bf16x8 a3 = *(const bf16x8*)&As_[(wy * 64 + 48 + l15) * 32 + quad * 8]; \
        const bf16x8 b0 = *(const bf16x8*)&Bs_[(wx * 64 +  0 + l15) * 32 + quad * 8]; \
        const bf16x8 b1 = *(const bf16x8*)&Bs_[(wx * 64 + 16 + l15) * 32 + quad * 8]; \
        const bf16x8 b2 = *(const bf16x8*)&Bs_[(wx * 64 + 32 + l15) * 32 + quad * 8]; \
        const bf16x8 b3 = *(const bf16x8*)&Bs_[(wx * 64 + 48 + l15) * 32 + quad * 8]; \
        MF(c00,a0,b0) MF(c01,a0,b1) MF(c02,a0,b2) MF(c03,a0,b3) \
        MF(c10,a1,b0) MF(c11,a1,b1) MF(c12,a1,b2) MF(c13,a1,b3) \
        MF(c20,a2,b0) MF(c21,a2,b1) MF(c22,a2,b2) MF(c23,a2,b3) \
        MF(c30,a3,b0) MF(c31,a3,b1) MF(c32,a3,b2) MF(c33,a3,b3) }

    O_STAGE(0, 0)
    O_STAGE(1, 32)
    {
        int cbuf = 0, sbuf = 2;
        for (int it = 0; it < 31; ++it) {
            asm volatile("s_waitcnt vmcnt(4)" ::: "memory");
            __builtin_amdgcn_s_barrier();
            if (it < 30) { O_STAGE(sbuf, (it + 2) * 32) }
            O_COMPUTE(cbuf)
            asm volatile("s_waitcnt lgkmcnt(0)" ::: "memory");
            cbuf = (cbuf == 2) ? 0 : cbuf + 1;
            sbuf = (sbuf == 2) ? 0 : sbuf + 1;
        }
        asm volatile("s_waitcnt vmcnt(0)" ::: "memory");
        __builtin_amdgcn_s_barrier();
        O_COMPUTE(cbuf)
    }

#define G_OUTST(mi,ni) { _Pragma("unroll") \
        for (int r = 0; r < 4; r++) { \
            const int m = m0 + wy * 64 + (mi) * 16 + quad * 4 + r; \
            const int n = n0 + wx * 64 + (ni) * 16 + l15; \
            out[(size_t)m * 1024 + n] = c##mi##ni[r] + x[(size_t)m * 1024 + n]; } }
    FOR_MN(G_OUTST)
}

// ---------------------------------------------------------------------------
// Causal quadratic attention. r18: QBLK=64 (4 waves x 16 q-rows), grid
// 1024 = 32 qt x 32 bh, 4 blocks/CU, balanced half-remap (31-x, x).
// setprio around MFMA clusters (r17). Mask only at kt==qt.
// ---------------------------------------------------------------------------
__global__ __launch_bounds__(256, 4) void attn_mfma(
    const unsigned short* __restrict__ qb, const unsigned short* __restrict__ kb,
    const unsigned short* __restrict__ vT, unsigned short* __restrict__ zb)
{
    __shared__ unsigned short Qs[64 * 72];
    __shared__ unsigned short Ks[64 * 72];
    __shared__ unsigned short Vs[64 * 72];   // rows = d, cols = k-token
    __shared__ unsigned short Pm[64 * 72];
    const int tid = threadIdx.x;

    // ---- balance remap: qt in 0..31 (64-row tiles); pair (31-x, x) ----
    const int bid = blockIdx.x;
    const int halfsz = gridDim.x >> 1;              // 512
    const int half = (bid >= halfsz) ? 1 : 0;
    const int r = bid - half * halfsz;              // 0..511
    const int qt = half ? (r & 15) : 31 - (r & 15);
    const int bh = r >> 4;                          // 0..31

    const int b = bh >> 4, h = bh & 15;
    const int lane = tid & 63, wq = tid >> 6;       // wq 0..3: 16 q-rows each
    const int l15 = lane & 15, quad = lane >> 4;
    const size_t tokbase = (size_t)b * 2048;
    const int q0 = qt * 64;

#pragma unroll
    for (int j = 0; j < 2; j++) {
        const int u = tid + j * 256;
        const int row = u >> 3, seg = (u & 7) * 8;
        bf16x8 v = *(const bf16x8*)(qb + (tokbase + q0 + row) * 1024 + h * 64 + seg);
        *(bf16x8*)&Qs[row * 72 + seg] = v;
    }
    __syncthreads();
    const bf16x8 aq0 = *(const bf16x8*)&Qs[(wq * 16 + l15) * 72 + quad * 8];
    const bf16x8 aq1 = *(const bf16x8*)&Qs[(wq * 16 + l15) * 72 + 32 + quad * 8];

    const int kr = tid >> 3;                        // 0..31
    const int sg = (tid & 7) * 8;

    bf16x8 pk0, pk1, pv0, pv1;
#define A_GLB(KT) { \
        pk0 = *(const bf16x8*)(kb + (tokbase + (KT) * 64 + kr) * 1024 + h * 64 + sg); \
        pk1 = *(const bf16x8*)(kb + (tokbase + (KT) * 64 + kr + 32) * 1024 + h * 64 + sg); \
        pv0 = *(const bf16x8*)(vT + ((size_t)bh * 64 + kr) * 2048 + (KT) * 64 + sg); \
        pv1 = *(const bf16x8*)(vT + ((size_t)bh * 64 + kr + 32) * 2048 + (KT) * 64 + sg); }

    f32x4 z_0 = {0.f,0.f,0.f,0.f}, z_1 = {0.f,0.f,0.f,0.f};
    f32x4 z_2 = {0.f,0.f,0.f,0.f}, z_3 = {0.f,0.f,0.f,0.f};

    const int nkt = qt + 1;
    A_GLB(0)
    for (int kt = 0; kt < nkt; kt++) {
        __syncthreads();
        *(bf16x8*)&Ks[kr * 72 + sg] = pk0;
        *(bf16x8*)&Ks[(kr + 32) * 72 + sg] = pk1;
        *(bf16x8*)&Vs[kr * 72 + sg] = pv0;
        *(bf16x8*)&Vs[(kr + 32) * 72 + sg] = pv1;
        __syncthreads();
        if (kt + 1 < nkt) A_GLB(kt + 1)

        f32x4 s_0 = {0.f,0.f,0.f,0.f}, s_1 = {0.f,0.f,0.f,0.f};
        f32x4 s_2 = {0.f,0.f,0.f,0.f}, s_3 = {0.f,0.f,0.f,0.f};
#define A_QKH(KS, AQ) { \
        bf16x8 b0 = *(const bf16x8*)&Ks[(l15) * 72 + (KS) * 32 + quad * 8]; \
        bf16x8 b1 = *(const bf16x8*)&Ks[(16 + l15) * 72 + (KS) * 32 + quad * 8]; \
        bf16x8 b2 = *(const bf16x8*)&Ks[(32 + l15) * 72 + (KS) * 32 + quad * 8]; \
        bf16x8 b3 = *(const bf16x8*)&Ks[(48 + l15) * 72 + (KS) * 32 + quad * 8]; \
        MF(s_0, AQ, b0) MF(s_1, AQ, b1) MF(s_2, AQ, b2) MF(s_3, AQ, b3) }
        __builtin_amdgcn_s_setprio(1);
        A_QKH(0, aq0)
        A_QKH(1, aq1)
        __builtin_amdgcn_s_setprio(0);

        const bool needmask = (kt == qt);
#define A_PSTORE(n) { \
        f32x4 p4 = s_##n * s_##n; \
        if (needmask) { _Pragma("unroll") \
            for (int r2 = 0; r2 < 4; r2++) \
                if (kt * 64 + (n) * 16 + l15 > q0 + wq * 16 + quad * 4 + r2) p4[r2] = 0.f; } \
        _Pragma("unroll") \
        for (int r2 = 0; r2 < 4; r2++) \
            Pm[(wq * 16 + quad * 4 + r2) * 72 + (n) * 16 + l15] = f2bf(p4[r2]); }
        A_PSTORE(0) A_PSTORE(1) A_PSTORE(2) A_PSTORE(3)

#define A_PVH(KS) { \
        bf16x8 ap = *(const bf16x8*)&Pm[(wq * 16 + l15) * 72 + (KS) * 32 + quad * 8]; \
        bf16x8 u0 = *(const bf16x8*)&Vs[(l15) * 72 + (KS) * 32 + quad * 8]; \
        bf16x8 u1 = *(const bf16x8*)&Vs[(16 + l15) * 72 + (KS) * 32 + quad * 8]; \
        bf16x8 u2 = *(const bf16x8*)&Vs[(32 + l15) * 72 + (KS) * 32 + quad * 8]; \
        bf16x8 u3 = *(const bf16x8*)&Vs[(48 + l15) * 72 + (KS) * 32 + quad * 8]; \
        MF(z_0, ap, u0) MF(z_1, ap, u1) MF(z_2, ap, u2) MF(z_3, ap, u3) }
        __builtin_amdgcn_s_setprio(1);
        A_PVH(0)
        A_PVH(1)
        __builtin_amdgcn_s_setprio(0);
    }

#define A_ZST(n) { _Pragma("unroll") \
        for (int r2 = 0; r2 < 4; r2++) \
            Pm[(wq * 16 + quad * 4 + r2) * 72 + (n) * 16 + l15] = f2bf(z_##n[r2]); }
    A_ZST(0) A_ZST(1) A_ZST(2) A_ZST(3)
#pragma unroll
    for (int it = 0; it < 2; it++) {
        const int linear = it * 64 + lane;
        const int row = linear >> 3, cb = linear & 7;
        *(bf16x8*)(zb + (tokbase + q0 + wq * 16 + row) * 1024 + h * 64 + cb * 8) =
            *(const bf16x8*)&Pm[(wq * 16 + row) * 72 + cb * 8];
    }
}

// ---------------------------------------------------------------------------
extern "C" void kernel_launch(void* const* d_in, const int* in_sizes, int n_in,
                              void* d_out, int out_size, void* d_ws, size_t ws_size,
                              hipStream_t stream)
{
    const float* x  = (const float*)d_in[0];
    const float* Wq = (const float*)d_in[1];
    const float* bq = (const float*)d_in[2];
    const float* Wk = (const float*)d_in[3];
    const float* bk = (const float*)d_in[4];
    const float* Wv = (const float*)d_in[5];
    const float* bv = (const float*)d_in[6];
    const float* Wo = (const float*)d_in[7];
    const float* nw = (const float*)d_in[8];
    float* out = (float*)d_out;

    const int D = 1024;
    const int M = in_sizes[0] / D;   // B*S = 4096

    unsigned short* xbb = (unsigned short*)d_ws;         // M*D
    unsigned short* Wqb = xbb + (size_t)M * D;           // D*D
    unsigned short* Wkb = Wqb + (size_t)D * D;
    unsigned short* Wvb = Wkb + (size_t)D * D;
    unsigned short* Wob = Wvb + (size_t)D * D;
    unsigned short* qbw = Wob + (size_t)D * D;           // M*D
    unsigned short* kbw = qbw + (size_t)M * D;
    unsigned short* vTw = kbw + (size_t)M * D;
    unsigned short* zbw = vTw + (size_t)M * D;

    const int nx4 = M * D / 4, nw4 = D * D / 4;
    const int ncvt = nx4 + 4 * nw4;
    cvt_all<<<(ncvt + 255) / 256, 256, 0, stream>>>(
        x, Wq, Wk, Wv, Wo, xbb, Wqb, Wkb, Wvb, Wob, nx4, nw4);

    gemm_qkvz<<<dim3(D / 128, M / 128, 3), 256, 0, stream>>>(
        xbb, Wqb, Wkb, Wvb, bq, bk, bv, nw, qbw, kbw, vTw);

    attn_mfma<<<dim3((M / 2048) * 16 * 32), 256, 0, stream>>>(qbw, kbw, vTw, zbw);

    gemm_out<<<dim3(D / 128, M / 128), 256, 0, stream>>>(zbw, Wob, x, out, M);
}